// Round 10
// baseline (71.492 us; speedup 1.0000x reference)
//
#include <hip/hip_runtime.h>

#define N 1024
#define D 128
#define PAD 132   // 128+4: rows 16B-aligned (528 B), bank stride 4 -> 2-way (free)

// ---------------------------------------------------------------------------
// ROUND-10: R9 structure with the scale-kernel coverage bug fixed.
// R9 bug: one wave per row but each lane read only rowp[l] (l<64) -> 256 of
// 1024 floats summed/scaled (absmax 8.37). Fix: each lane handles 4 float4s
// at stride 64 (l, l+64, l+128, l+192) -> full row.
//
// Scores kernel: R8's proven symmetric core (71.0 us best), epilogue writes
// exp values only (direct + LDS-transposed mirror tile), no partial-sum
// machinery, no workspace. Scale kernel re-derives row sums from E (L2-hot).
// ---------------------------------------------------------------------------
__global__ __launch_bounds__(128, 2) void scores_kernel(
    const float* __restrict__ x, const float* __restrict__ w,
    const float* __restrict__ bias, float* __restrict__ E) {
  __shared__ float sxi[16 * PAD];    // 8.4 KB
  __shared__ float sxj[32 * PAD];    // 16.9 KB
  __shared__ float sw[D];            // 512 B
  __shared__ float ldst[16 * 33];    // 2.1 KB transpose buffer

  const int t = threadIdx.x;

  // ---- triangular enumeration (wave-uniform scalar math) -------------------
  const int tt = blockIdx.x >> 1;    // tile index 0..527
  const int h  = blockIdx.x & 1;     // row-half
  int q = (int)((sqrtf(8.0f * (float)tt + 1.0f) - 1.0f) * 0.5f);
  while ((q + 1) * (q + 2) / 2 <= tt) ++q;   // fixup for sqrt rounding
  while (q * (q + 1) / 2 > tt) --q;
  const int p  = tt - q * (q + 1) / 2;       // p <= q
  const int bi = p * 32 + h * 16;    // 16 rows
  const int bj = q * 32;             // 32 cols

  // ---- stage xi(16 rows) + xj(32 rows) + w: coalesced float4 ---------------
  {
    const int c  = t & 31;   // float4 column
    const int r0 = t >> 5;   // 0..3
    #pragma unroll
    for (int k = 0; k < 4; ++k) {    // 16 rows of xi
      const int r = r0 + k * 4;
      *reinterpret_cast<float4*>(&sxi[r * PAD + c * 4]) =
          reinterpret_cast<const float4*>(x)[(bi + r) * 32 + c];
    }
    #pragma unroll
    for (int k = 0; k < 8; ++k) {    // 32 rows of xj
      const int r = r0 + k * 4;
      *reinterpret_cast<float4*>(&sxj[r * PAD + c * 4]) =
          reinterpret_cast<const float4*>(x)[(bj + r) * 32 + c];
    }
    if (t < 32)
      *reinterpret_cast<float4*>(&sw[t * 4]) =
          reinterpret_cast<const float4*>(w)[t];
  }
  __syncthreads();

  const int tx = t & 15;   // j = tx + 16*b, b=0..1
  const int ty = t >> 4;   // i = ty + 8*a,  a=0..1

  float acc[2][2];
  acc[0][0] = acc[0][1] = acc[1][0] = acc[1][1] = 0.f;

  #pragma unroll 4
  for (int dc = 0; dc < 32; ++dc) {   // 32 chunks of 4 d-values
    const int d = dc * 4;
    const float4 W = *reinterpret_cast<const float4*>(&sw[d]);  // broadcast
    float4 A[2], B[2];
    #pragma unroll
    for (int a = 0; a < 2; ++a)   // 4 addrs/wave, 16-lane broadcast
      A[a] = *reinterpret_cast<const float4*>(&sxi[(ty + 8 * a) * PAD + d]);
    #pragma unroll
    for (int b = 0; b < 2; ++b)   // 16 addrs/wave, 2-way alias (free)
      B[b] = *reinterpret_cast<const float4*>(&sxj[(tx + 16 * b) * PAD + d]);

    #pragma unroll
    for (int a = 0; a < 2; ++a) {
      #pragma unroll
      for (int b = 0; b < 2; ++b) {
        float v = acc[a][b];
        v = fmaf(fabsf(A[a].x - B[b].x), W.x, v);
        v = fmaf(fabsf(A[a].y - B[b].y), W.y, v);
        v = fmaf(fabsf(A[a].z - B[b].z), W.z, v);
        v = fmaf(fabsf(A[a].w - B[b].w), W.w, v);
        acc[a][b] = v;
      }
    }
  }

  // ---- epilogue: bias + relu + exp, direct write (no partials) -------------
  const float bv = bias[0];
  float e[2][2];
  #pragma unroll
  for (int a = 0; a < 2; ++a)
    #pragma unroll
    for (int b = 0; b < 2; ++b)
      e[a][b] = __expf(fmaxf(acc[a][b] + bv, 0.f));

  #pragma unroll
  for (int a = 0; a < 2; ++a) {
    const int row = bi + ty + 8 * a;
    #pragma unroll
    for (int b = 0; b < 2; ++b)
      E[row * N + bj + tx + 16 * b] = e[a][b];
  }

  // ---- transpose mirror tile (off-diagonal blocks only) --------------------
  if (p != q) {
    #pragma unroll
    for (int a = 0; a < 2; ++a)
      #pragma unroll
      for (int b = 0; b < 2; ++b)
        ldst[(ty + 8 * a) * 33 + tx + 16 * b] = e[a][b];
    __syncthreads();   // uniform branch: p,q wave-uniform for whole block

    // read transposed: thread -> out-row rj (=orig col), 4 consecutive cols
    const int rj = t >> 2;          // 0..31
    const int c0 = (t & 3) * 4;     // 0,4,8,12
    const float v0 = ldst[(c0 + 0) * 33 + rj];
    const float v1 = ldst[(c0 + 1) * 33 + rj];
    const float v2 = ldst[(c0 + 2) * 33 + rj];
    const float v3 = ldst[(c0 + 3) * 33 + rj];
    *reinterpret_cast<float4*>(&E[(bj + rj) * N + bi + c0]) =
        make_float4(v0, v1, v2, v3);
  }
}

// ---------------------------------------------------------------------------
// Phase B: row softmax-normalize from E. One wave per row; lane l covers
// float4 indices l, l+64, l+128, l+192 (full 1024 floats). Shuffle-reduce,
// scale, write back. No LDS, no barriers, no ws. 256 blocks x 256 thr.
// ---------------------------------------------------------------------------
__global__ __launch_bounds__(256) void scale_kernel(float* __restrict__ S) {
  const int row = blockIdx.x * 4 + (threadIdx.x >> 6);
  const int l   = threadIdx.x & 63;

  float4* rowp = reinterpret_cast<float4*>(S + row * N);
  float4 v[4];
  float s = 0.f;
  #pragma unroll
  for (int k = 0; k < 4; ++k) {
    v[k] = rowp[l + 64 * k];
    s += (v[k].x + v[k].y) + (v[k].z + v[k].w);
  }
  #pragma unroll
  for (int o = 1; o < 64; o <<= 1) s += __shfl_xor(s, o, 64);
  const float r = 1.0f / s;
  #pragma unroll
  for (int k = 0; k < 4; ++k) {
    v[k].x *= r; v[k].y *= r; v[k].z *= r; v[k].w *= r;
    rowp[l + 64 * k] = v[k];
  }
}

extern "C" void kernel_launch(void* const* d_in, const int* in_sizes, int n_in,
                              void* d_out, int out_size, void* d_ws, size_t ws_size,
                              hipStream_t stream) {
  const float* x = (const float*)d_in[0];
  const float* w = (const float*)d_in[1];
  const float* b = (const float*)d_in[2];
  float* out = (float*)d_out;

  scores_kernel<<<1056, 128, 0, stream>>>(x, w, b, out);
  scale_kernel<<<256, 256, 0, stream>>>(out);
}